// Round 11
// baseline (168.894 us; speedup 1.0000x reference)
//
#include <hip/hip_runtime.h>
#include <hip/hip_bf16.h>
#include <cstdint>
#include <cstddef>

// LSTMCell: gates = [input|hx] @ [Wih|Whh]^T + b_ih + b_hh  (4096 x 4096 x K=2048)
// Round 11: single-product f16 GEMM (absmax 0.051 verified), R8's proven 2-phase
// counted-vmcnt protocol, with W loaded DIRECT TO REGISTERS (double-buffered, one
// step ahead, L2-resident pattern: 16 rows x 128 contiguous B per load) — removes
// W's LDS DMA + ds_reads. A stays in LDS ring-3 (4x cross-wave reuse), 48 KB.

#define B_ROWS 4096
#define HDIM   1024
#define KDIM   2048
#define BM     256
#define BK     32
#define T_STEPS (KDIM / BK)   // 64

typedef unsigned short u16;
using f32x4  = __attribute__((ext_vector_type(4))) float;
using short8 = __attribute__((ext_vector_type(8))) short;
using half8  = __attribute__((ext_vector_type(8))) _Float16;

__device__ __forceinline__ u16 f2h_bits(float f) {
    _Float16 h = (_Float16)f;                    // v_cvt_f16_f32, RTN
    return __builtin_bit_cast(u16, h);
}

// ---------------- pack: f32 -> f16, concat K-dim ----------------
__global__ void pack_kernel(const float* __restrict__ input, const float* __restrict__ hx,
                            const float* __restrict__ wih, const float* __restrict__ whh,
                            u16* __restrict__ Af, u16* __restrict__ Wf)
{
    const int PER = (B_ROWS * KDIM) / 4;  // float4 groups per matrix
    int stride = gridDim.x * blockDim.x;
    for (int i = blockIdx.x * blockDim.x + threadIdx.x; i < 2 * PER; i += stride) {
        int isW = (i >= PER) ? 1 : 0;
        int e = i - isW * PER;
        int row = e >> 9;            // 512 float4-groups per row of 2048
        int k = (e & 511) << 2;
        const float* s0 = isW ? wih : input;
        const float* s1 = isW ? whh : hx;
        const float* src = (k < 1024) ? (s0 + (size_t)row * 1024 + k)
                                      : (s1 + (size_t)row * 1024 + (k - 1024));
        float4 v = *(const float4*)src;
        size_t doff = (size_t)row * KDIM + k;
        u16* dst = (isW ? Wf : Af) + doff;
        *(ushort4*)dst = make_ushort4(f2h_bits(v.x), f2h_bits(v.y),
                                      f2h_bits(v.z), f2h_bits(v.w));
    }
}

// ---------------- fused GEMM + LSTM epilogue ----------------
__device__ __forceinline__ void gload16(const void* g, void* l) {
    __builtin_amdgcn_global_load_lds((const __attribute__((address_space(1))) void*)g,
                                     (__attribute__((address_space(3))) void*)l, 16, 0, 0);
}
__device__ __forceinline__ float sigmf(float x) { return 1.0f / (1.0f + __expf(-x)); }
__device__ __forceinline__ float tanhfast(float x) { return 1.0f - 2.0f / (1.0f + __expf(2.0f * x)); }

__launch_bounds__(512, 2)
__global__ void lstm_fused(const u16* __restrict__ Afp, const u16* __restrict__ Wfp,
                           const float* __restrict__ cx, const float* __restrict__ eps_c,
                           const float* __restrict__ eps_h,
                           const float* __restrict__ bias_ih, const float* __restrict__ bias_hh,
                           const float* __restrict__ noise_q, const float* __restrict__ noise_e,
                           float* __restrict__ out)
{
    // A-only LDS ring: [sb(3)][kc(4)][row(256)][8] u16 = 48 KB. Linear for
    // global_load_lds, conflict-free ds_read_b128 (0 conflicts R1-R10).
    __shared__ __align__(16) u16 lA[3][4][256][8];

    int bid = blockIdx.x;
    // XCD-bijective swizzle: XCD x gets w in [32x,32x+32) -> 2 hq values
    // (W working set 2 MB, L2-resident) x all 16 A panels.
    int w = (bid & 7) * 32 + (bid >> 3);
    int mi = w & 15;          // 16 M-chunks of 256 rows
    int hq = w >> 4;          // 16 h-chunks of 64 cols (x4 gates = 256 gate-cols)
    int bm0 = mi * BM;
    int h0 = hq * 64;

    int tid  = threadIdx.x;
    int lane = tid & 63;
    int wid  = tid >> 6;      // 0..7
    int wm   = wid >> 2;      // M half (128 rows)
    int wn   = wid & 3;       // h quarter (16 cols x 4 gates = 64 gate-cols)

    // ---- A staging mapping: thread -> (row = tid&255, kc base = tid>>8), 2 loads ----
    int rSt = tid & 255;
    int kS  = tid >> 8;       // 0/1
    const u16* Asrc = Afp + (size_t)(bm0 + rSt) * KDIM;

#define STG_A(sb, t_) do { \
        gload16(Asrc + (t_) * 32 + kS * 8,       &lA[sb][kS][rSt][0]);     \
        gload16(Asrc + (t_) * 32 + (kS + 2) * 8, &lA[sb][kS + 2][rSt][0]); } while (0)

    // ---- fragment indices ----
    int fk = lane >> 4, fr = lane & 15;

    // ---- W-fragment global pointers (per-lane; 16 rows x 128 contiguous B per load) ----
    const u16* WregB[4];
#pragma unroll
    for (int g = 0; g < 4; ++g)
        WregB[g] = Wfp + (size_t)(g * 1024 + h0 + wn * 16 + fr) * KDIM + fk * 8;

    f32x4 acc[8][4];   // [m-frag][gate]
#pragma unroll
    for (int m = 0; m < 8; ++m)
#pragma unroll
        for (int g = 0; g < 4; ++g)
            acc[m][g] = (f32x4){0.f, 0.f, 0.f, 0.f};

#define LD8(p) __builtin_bit_cast(half8, *(const short8*)(p))

    // ---- prologue: W(0) -> wfA ; stage A(0)->sb0, A(1)->sb1 ; drain all but sb1 ----
    half8 wfA[4], wfB[4];
#pragma unroll
    for (int g = 0; g < 4; ++g) wfA[g] = LD8(WregB[g]);
    STG_A(0, 0);
    STG_A(1, 1);
    asm volatile("s_waitcnt vmcnt(2)");   // W(0) + sb0 landed; sb1 in flight
    __builtin_amdgcn_s_barrier();

#define MFMA16(mb, A0, A1, A2, A3, WF) do { \
        _Pragma("unroll") \
        for (int g = 0; g < 4; ++g) { \
            acc[(mb)][g]     = __builtin_amdgcn_mfma_f32_16x16x32_f16(A0, WF[g], acc[(mb)][g], 0, 0, 0); \
            acc[(mb) + 1][g] = __builtin_amdgcn_mfma_f32_16x16x32_f16(A1, WF[g], acc[(mb) + 1][g], 0, 0, 0); \
        } \
        _Pragma("unroll") \
        for (int g = 0; g < 4; ++g) { \
            acc[(mb) + 2][g] = __builtin_amdgcn_mfma_f32_16x16x32_f16(A2, WF[g], acc[(mb) + 2][g], 0, 0, 0); \
            acc[(mb) + 3][g] = __builtin_amdgcn_mfma_f32_16x16x32_f16(A3, WF[g], acc[(mb) + 3][g], 0, 0, 0); \
        } \
    } while (0)

    // One K-step. WFU = W(t) regs (loaded last step); WFL gets W(t+1).
#define STEP(t_, WFU, WFL) do { \
        const int scur = (t_) % 3; \
        const int spre = ((t_) + 2) % 3; \
        const u16* pA = &lA[scur][fk][wm * 128 + fr][0]; \
        half8 a0, a1, a2, a3, a4, a5, a6, a7; \
        /* Phase A: issue W(t+1) + stage A(t+2) ; read A m0-3 */ \
        if ((t_) < T_STEPS - 1) { \
            _Pragma("unroll") \
            for (int g = 0; g < 4; ++g) WFL[g] = LD8(WregB[g] + ((t_) + 1) * 32); \
        } \
        if ((t_) < T_STEPS - 2) STG_A(spre, (t_) + 2); \
        a0 = LD8(pA);       a1 = LD8(pA + 128); \
        a2 = LD8(pA + 256); a3 = LD8(pA + 384); \
        __builtin_amdgcn_s_barrier(); \
        asm volatile("s_waitcnt lgkmcnt(0)"); \
        __builtin_amdgcn_sched_barrier(0); \
        __builtin_amdgcn_s_setprio(1); \
        MFMA16(0, a0, a1, a2, a3, WFU); \
        __builtin_amdgcn_s_setprio(0); \
        __builtin_amdgcn_s_barrier(); \
        /* Phase B: read A m4-7 ; MFMA ; counted vmcnt */ \
        a4 = LD8(pA + 512); a5 = LD8(pA + 640); \
        a6 = LD8(pA + 768); a7 = LD8(pA + 896); \
        __builtin_amdgcn_s_barrier(); \
        asm volatile("s_waitcnt lgkmcnt(0)"); \
        __builtin_amdgcn_sched_barrier(0); \
        __builtin_amdgcn_s_setprio(1); \
        MFMA16(4, a4, a5, a6, a7, WFU); \
        __builtin_amdgcn_s_setprio(0); \
        asm volatile("s_waitcnt vmcnt(2)");  /* drain W(t+1)+A(t+1); A(t+2) in flight */ \
        __builtin_amdgcn_s_barrier(); \
    } while (0)

#pragma unroll 1
    for (int tt = 0; tt < T_STEPS; tt += 2) {
        STEP(tt,     wfA, wfB);
        STEP(tt + 1, wfB, wfA);
    }

    // ---- epilogue: all 4 gates for (r,h) are lane-local ----
    float sq_e = sqrtf(noise_e[0]);
    float sq_q = sqrtf(noise_q[0]);
    int h = h0 + wn * 16 + fr;
    float bsum[4];
#pragma unroll
    for (int g = 0; g < 4; ++g)
        bsum[g] = bias_ih[g * 1024 + h] + bias_hh[g * 1024 + h];
#pragma unroll
    for (int m = 0; m < 8; ++m) {
        int r0 = bm0 + wm * 128 + m * 16 + fk * 4;
#pragma unroll
        for (int j = 0; j < 4; ++j) {
            int r = r0 + j;
            float gi = acc[m][0][j] + bsum[0];
            float gf = acc[m][1][j] + bsum[1];
            float gc = acc[m][2][j] + bsum[2];
            float go = acc[m][3][j] + bsum[3];
            float ig = sigmf(gi), fg = sigmf(gf);
            float cg = tanhfast(gc), og = sigmf(go);
            size_t off = (size_t)r * HDIM + h;
            float cyv = fg * cx[off] + ig * cg + sq_e * eps_c[off];
            float hyv = og * tanhfast(cyv) + sq_q * eps_h[off];
            out[off] = hyv;                                 // hy
            out[(size_t)B_ROWS * HDIM + off] = cyv;         // cy
        }
    }
}

extern "C" void kernel_launch(void* const* d_in, const int* in_sizes, int n_in,
                              void* d_out, int out_size, void* d_ws, size_t ws_size,
                              hipStream_t stream)
{
    const float* input = (const float*)d_in[0];
    const float* hx    = (const float*)d_in[1];
    const float* cx    = (const float*)d_in[2];
    const float* nq    = (const float*)d_in[3];
    const float* ne    = (const float*)d_in[4];
    const float* wih   = (const float*)d_in[5];
    const float* whh   = (const float*)d_in[6];
    const float* bih   = (const float*)d_in[7];
    const float* bhh   = (const float*)d_in[8];
    const float* epsc  = (const float*)d_in[9];
    const float* epsh  = (const float*)d_in[10];
    float* out = (float*)d_out;

    u16* Af = (u16*)d_ws;
    u16* Wf = Af + (size_t)B_ROWS * KDIM;   // 32 MB of ws total

    hipLaunchKernelGGL(pack_kernel, dim3(2048), dim3(256), 0, stream,
                       input, hx, wih, whh, Af, Wf);
    hipLaunchKernelGGL(lstm_fused, dim3(256), dim3(512), 0, stream,
                       Af, Wf, cx, epsc, epsh, bih, bhh, nq, ne, out);
}

// Round 12
// 157.541 us; speedup vs baseline: 1.0721x; 1.0721x over previous
//
#include <hip/hip_runtime.h>
#include <hip/hip_bf16.h>
#include <cstdint>
#include <cstddef>

// LSTMCell: gates = [input|hx] @ [Wih|Whh]^T + b_ih + b_hh  (4096 x 4096 x K=2048)
// Round 12: single-product f16 GEMM (absmax 0.051 verified R8-R11). R8's ring-3 +
// counted-vmcnt, but ONE barrier + ONE vmcnt per K-step and NO manual lgkm waits:
// the compiler interleaves ds_read -> MFMA with fine-grained lgkmcnt (m97 behavior),
// tail reads hide under early MFMAs. Safety: in-order issue => all reads issued
// before barrier; ring distance-2 => STG(t+2) WAR-safe; vmcnt(4) drains t+1 only.

#define B_ROWS 4096
#define HDIM   1024
#define KDIM   2048
#define BM     256
#define BK     32
#define T_STEPS (KDIM / BK)   // 64

typedef unsigned short u16;
using f32x4  = __attribute__((ext_vector_type(4))) float;
using short8 = __attribute__((ext_vector_type(8))) short;
using half8  = __attribute__((ext_vector_type(8))) _Float16;

__device__ __forceinline__ u16 f2h_bits(float f) {
    _Float16 h = (_Float16)f;                    // v_cvt_f16_f32, RTN
    return __builtin_bit_cast(u16, h);
}

// ---------------- pack: f32 -> f16, concat K-dim ----------------
__global__ void pack_kernel(const float* __restrict__ input, const float* __restrict__ hx,
                            const float* __restrict__ wih, const float* __restrict__ whh,
                            u16* __restrict__ Af, u16* __restrict__ Wf)
{
    const int PER = (B_ROWS * KDIM) / 4;  // float4 groups per matrix
    int stride = gridDim.x * blockDim.x;
    for (int i = blockIdx.x * blockDim.x + threadIdx.x; i < 2 * PER; i += stride) {
        int isW = (i >= PER) ? 1 : 0;
        int e = i - isW * PER;
        int row = e >> 9;            // 512 float4-groups per row of 2048
        int k = (e & 511) << 2;
        const float* s0 = isW ? wih : input;
        const float* s1 = isW ? whh : hx;
        const float* src = (k < 1024) ? (s0 + (size_t)row * 1024 + k)
                                      : (s1 + (size_t)row * 1024 + (k - 1024));
        float4 v = *(const float4*)src;
        size_t doff = (size_t)row * KDIM + k;
        u16* dst = (isW ? Wf : Af) + doff;
        *(ushort4*)dst = make_ushort4(f2h_bits(v.x), f2h_bits(v.y),
                                      f2h_bits(v.z), f2h_bits(v.w));
    }
}

// ---------------- fused GEMM + LSTM epilogue ----------------
__device__ __forceinline__ void gload16(const void* g, void* l) {
    __builtin_amdgcn_global_load_lds((const __attribute__((address_space(1))) void*)g,
                                     (__attribute__((address_space(3))) void*)l, 16, 0, 0);
}
__device__ __forceinline__ float sigmf(float x) { return 1.0f / (1.0f + __expf(-x)); }
__device__ __forceinline__ float tanhfast(float x) { return 1.0f - 2.0f / (1.0f + __expf(2.0f * x)); }

__launch_bounds__(512, 2)
__global__ void lstm_fused(const u16* __restrict__ Afp, const u16* __restrict__ Wfp,
                           const float* __restrict__ cx, const float* __restrict__ eps_c,
                           const float* __restrict__ eps_h,
                           const float* __restrict__ bias_ih, const float* __restrict__ bias_hh,
                           const float* __restrict__ noise_q, const float* __restrict__ noise_e,
                           float* __restrict__ out)
{
    // k-chunk-panel layout [sb(3)][kc(4)][row(256)][8] u16 — linear for global_load_lds,
    // conflict-free ds_read_b128 (0 conflicts measured R1-R11). 96 KB total.
    __shared__ __align__(16) u16 lA[3][4][256][8];
    __shared__ __align__(16) u16 lW[3][4][256][8];

    int bid = blockIdx.x;
    // XCD-bijective swizzle (256 % 8 == 0): XCD x gets w in [32x,32x+32) -> 2 hq
    // values (W working set 2 MB, L2-resident) x all 16 A panels.
    int w = (bid & 7) * 32 + (bid >> 3);
    int mi = w & 15;          // 16 M-chunks of 256 rows
    int hq = w >> 4;          // 16 h-chunks of 64 cols (x4 gates = 256 gate-cols)
    int bm0 = mi * BM;
    int h0 = hq * 64;

    int tid  = threadIdx.x;
    int lane = tid & 63;
    int wid  = tid >> 6;      // 0..7
    int wm   = wid >> 2;      // M half (128 rows)
    int wn   = wid & 3;       // h quarter (16 cols x 4 gates = 64 gate-cols)

    // ---- staging mapping: thread -> (row = tid&255, kc base = tid>>8), 2 loads kc,kc+2 ----
    int rSt = tid & 255;
    int kS  = tid >> 8;       // 0/1
    const u16* Asrc = Afp + (size_t)(bm0 + rSt) * KDIM;
    // LDS W row n <-> global gate row: gate = n>>6, h = h0 + (n&63)
    int wgrow = (rSt >> 6) * 1024 + h0 + (rSt & 63);
    const u16* Wsrc = Wfp + (size_t)wgrow * KDIM;

#define STG_A(sb, t_) do { \
        gload16(Asrc + (t_) * 32 + kS * 8,       &lA[sb][kS][rSt][0]);     \
        gload16(Asrc + (t_) * 32 + (kS + 2) * 8, &lA[sb][kS + 2][rSt][0]); } while (0)
#define STG_W(sb, t_) do { \
        gload16(Wsrc + (t_) * 32 + kS * 8,       &lW[sb][kS][rSt][0]);     \
        gload16(Wsrc + (t_) * 32 + (kS + 2) * 8, &lW[sb][kS + 2][rSt][0]); } while (0)

    // ---- fragment read indices ----
    int fk = lane >> 4, fr = lane & 15;

    f32x4 acc[8][4];   // [m-frag][gate]
#pragma unroll
    for (int m = 0; m < 8; ++m)
#pragma unroll
        for (int g = 0; g < 4; ++g)
            acc[m][g] = (f32x4){0.f, 0.f, 0.f, 0.f};

    // ---- prologue: stage steps 0,1 into sb0,sb1; wait only sb0 (4 newest in flight) ----
    STG_A(0, 0); STG_W(0, 0);
    STG_A(1, 1); STG_W(1, 1);
    asm volatile("s_waitcnt vmcnt(4)");
    __builtin_amdgcn_s_barrier();

#define LD8(p) __builtin_bit_cast(half8, *(const short8*)(p))

#define PH_MFMA(mb, A0, A1, A2, A3) do { \
        _Pragma("unroll") \
        for (int g = 0; g < 4; ++g) { \
            acc[(mb)][g]     = __builtin_amdgcn_mfma_f32_16x16x32_f16(A0, wf[g], acc[(mb)][g], 0, 0, 0); \
            acc[(mb) + 1][g] = __builtin_amdgcn_mfma_f32_16x16x32_f16(A1, wf[g], acc[(mb) + 1][g], 0, 0, 0); \
        } \
        _Pragma("unroll") \
        for (int g = 0; g < 4; ++g) { \
            acc[(mb) + 2][g] = __builtin_amdgcn_mfma_f32_16x16x32_f16(A2, wf[g], acc[(mb) + 2][g], 0, 0, 0); \
            acc[(mb) + 3][g] = __builtin_amdgcn_mfma_f32_16x16x32_f16(A3, wf[g], acc[(mb) + 3][g], 0, 0, 0); \
        } \
    } while (0)

#pragma unroll 1
    for (int t = 0; t < T_STEPS; ++t) {
        const int scur = t % 3;
        const int spre = (t + 2) % 3;
        const bool pre = (t < T_STEPS - 2);
        const u16* pA = &lA[scur][fk][wm * 128 + fr][0];
        const u16* pW = &lW[scur][fk][wn * 16 + fr][0];

        half8 wf[4], a0, a1, a2, a3, a4, a5, a6, a7;

        // ---- stage t+2 first (long-latency DMA; pinned ahead of the reads) ----
        if (pre) { STG_A(spre, t + 2); STG_W(spre, t + 2); }
        __builtin_amdgcn_sched_barrier(0);

        // ---- 12 ds_reads; NO manual lgkm wait — compiler interleaves with MFMA ----
        wf[0] = LD8(pW);        wf[1] = LD8(pW + 512);
        wf[2] = LD8(pW + 1024); wf[3] = LD8(pW + 1536);
        a0 = LD8(pA);           a1 = LD8(pA + 128);
        a2 = LD8(pA + 256);     a3 = LD8(pA + 384);
        a4 = LD8(pA + 512);     a5 = LD8(pA + 640);
        a6 = LD8(pA + 768);     a7 = LD8(pA + 896);

        __builtin_amdgcn_s_setprio(1);
        PH_MFMA(0, a0, a1, a2, a3);
        PH_MFMA(4, a4, a5, a6, a7);
        __builtin_amdgcn_s_setprio(0);

        if (pre) asm volatile("s_waitcnt vmcnt(4)");   // t+1 landed; t+2 in flight
        else     asm volatile("s_waitcnt vmcnt(0)");
        __builtin_amdgcn_s_barrier();                  // single barrier per step
    }

    // ---- epilogue: all 4 gates for (r,h) are lane-local ----
    float sq_e = sqrtf(noise_e[0]);
    float sq_q = sqrtf(noise_q[0]);
    int h = h0 + wn * 16 + fr;
    float bsum[4];
#pragma unroll
    for (int g = 0; g < 4; ++g)
        bsum[g] = bias_ih[g * 1024 + h] + bias_hh[g * 1024 + h];
#pragma unroll
    for (int m = 0; m < 8; ++m) {
        int r0 = bm0 + wm * 128 + m * 16 + fk * 4;
#pragma unroll
        for (int j = 0; j < 4; ++j) {
            int r = r0 + j;
            float gi = acc[m][0][j] + bsum[0];
            float gf = acc[m][1][j] + bsum[1];
            float gc = acc[m][2][j] + bsum[2];
            float go = acc[m][3][j] + bsum[3];
            float ig = sigmf(gi), fg = sigmf(gf);
            float cg = tanhfast(gc), og = sigmf(go);
            size_t off = (size_t)r * HDIM + h;
            float cyv = fg * cx[off] + ig * cg + sq_e * eps_c[off];
            float hyv = og * tanhfast(cyv) + sq_q * eps_h[off];
            out[off] = hyv;                                 // hy
            out[(size_t)B_ROWS * HDIM + off] = cyv;         // cy
        }
    }
}

extern "C" void kernel_launch(void* const* d_in, const int* in_sizes, int n_in,
                              void* d_out, int out_size, void* d_ws, size_t ws_size,
                              hipStream_t stream)
{
    const float* input = (const float*)d_in[0];
    const float* hx    = (const float*)d_in[1];
    const float* cx    = (const float*)d_in[2];
    const float* nq    = (const float*)d_in[3];
    const float* ne    = (const float*)d_in[4];
    const float* wih   = (const float*)d_in[5];
    const float* whh   = (const float*)d_in[6];
    const float* bih   = (const float*)d_in[7];
    const float* bhh   = (const float*)d_in[8];
    const float* epsc  = (const float*)d_in[9];
    const float* epsh  = (const float*)d_in[10];
    float* out = (float*)d_out;

    u16* Af = (u16*)d_ws;
    u16* Wf = Af + (size_t)B_ROWS * KDIM;   // 32 MB of ws total

    hipLaunchKernelGGL(pack_kernel, dim3(2048), dim3(256), 0, stream,
                       input, hx, wih, whh, Af, Wf);
    hipLaunchKernelGGL(lstm_fused, dim3(256), dim3(512), 0, stream,
                       Af, Wf, cx, epsc, epsh, bih, bhh, nq, ne, out);
}

// Round 13
// 101.098 us; speedup vs baseline: 1.6706x; 1.5583x over previous
//
#include <hip/hip_runtime.h>
#include <hip/hip_bf16.h>
#include <cstdint>
#include <cstddef>

// LSTMCell: gates = [input|hx] @ [Wih|Whh]^T + b_ih + b_hh  (4096 x 4096 x K=2048)
// Round 13: single-product f16 GEMM (absmax 0.051 verified R8-R12), NO LDS, NO
// BARRIERS. Pack emits fragment-major layouts so every MFMA fragment load is one
// coalesced global_load_dwordx4 (1 KB/wave) from L2-resident data. GEMM = plain-HIP
// software-pipelined register double-buffer; waves fully self-paced; compiler's
// automatic waitcnt insertion guarantees correctness.
//
// A layout: [mi(16)][wm(2)][kt(64)][m(8)][lane(64)][8 u16]
// W layout: [hq(16)][wn(4)][kt(64)][g(4)][lane(64)][8 u16]
// lane = fk*16+fr supplies A[row=...+fr][k=kt*32+fk*8..+8] (MFMA frag mapping).

#define B_ROWS 4096
#define HDIM   1024
#define KDIM   2048
#define BM     256
#define T_STEPS 64

typedef unsigned short u16;
using f32x4  = __attribute__((ext_vector_type(4))) float;
using short8 = __attribute__((ext_vector_type(8))) short;
using half8  = __attribute__((ext_vector_type(8))) _Float16;

__device__ __forceinline__ u16 f2h_bits(float f) {
    _Float16 h = (_Float16)f;                    // v_cvt_f16_f32, RTN
    return __builtin_bit_cast(u16, h);
}

// ---------------- pack: f32 -> f16 fragment-major ----------------
__global__ void pack_kernel(const float* __restrict__ input, const float* __restrict__ hx,
                            const float* __restrict__ wih, const float* __restrict__ whh,
                            u16* __restrict__ Ap, u16* __restrict__ Wp)
{
    const int NA = 16 * 2 * 64 * 8 * 64;   // 1,048,576 16B-groups
    const int NW = 16 * 4 * 64 * 4 * 64;   // 1,048,576
    int stride = gridDim.x * blockDim.x;
    for (int i = blockIdx.x * blockDim.x + threadIdx.x; i < NA + NW; i += stride) {
        int isW = (i >= NA) ? 1 : 0;
        int e = isW ? i - NA : i;
        int lane = e & 63;
        int fr = lane & 15, fk = lane >> 4;
        int kt = isW ? ((e >> 8) & 63) : ((e >> 9) & 63);
        int k  = kt * 32 + fk * 8;
        int row;
        if (isW) {
            int g  = (e >> 6) & 3;
            int wn = (e >> 14) & 3;
            int hqq = e >> 16;
            row = g * 1024 + hqq * 64 + wn * 16 + fr;
        } else {
            int m  = (e >> 6) & 7;
            int wmm = (e >> 15) & 1;
            int mii = e >> 16;
            row = mii * 256 + wmm * 128 + m * 16 + fr;
        }
        const float* s0 = isW ? wih : input;
        const float* s1 = isW ? whh : hx;
        const float* src = (k < 1024) ? (s0 + (size_t)row * 1024 + k)
                                      : (s1 + (size_t)row * 1024 + (k - 1024));
        float4 v0 = *(const float4*)src;
        float4 v1 = *(const float4*)(src + 4);
        u16* dst = (isW ? Wp : Ap) + (size_t)e * 8;
        *(ushort4*)dst = make_ushort4(f2h_bits(v0.x), f2h_bits(v0.y),
                                      f2h_bits(v0.z), f2h_bits(v0.w));
        *(ushort4*)(dst + 4) = make_ushort4(f2h_bits(v1.x), f2h_bits(v1.y),
                                            f2h_bits(v1.z), f2h_bits(v1.w));
    }
}

// ---------------- fused GEMM + LSTM epilogue (no LDS, no barriers) ----------------
__device__ __forceinline__ float sigmf(float x) { return 1.0f / (1.0f + __expf(-x)); }
__device__ __forceinline__ float tanhfast(float x) { return 1.0f - 2.0f / (1.0f + __expf(2.0f * x)); }

__launch_bounds__(512, 1)
__global__ void lstm_fused(const u16* __restrict__ Ap, const u16* __restrict__ Wp,
                           const float* __restrict__ cx, const float* __restrict__ eps_c,
                           const float* __restrict__ eps_h,
                           const float* __restrict__ bias_ih, const float* __restrict__ bias_hh,
                           const float* __restrict__ noise_q, const float* __restrict__ noise_e,
                           float* __restrict__ out)
{
    int bid = blockIdx.x;
    // XCD-bijective swizzle: XCD x gets w in [32x,32x+32) -> 2 hq values
    // (W slice 2 MB packed, L2-resident) x all 16 A panels (L3-resident).
    int w = (bid & 7) * 32 + (bid >> 3);
    int mi = w & 15;          // 16 M-chunks of 256 rows
    int hq = w >> 4;          // 16 h-chunks of 64 cols (x4 gates)
    int bm0 = mi * BM;
    int h0 = hq * 64;

    int tid  = threadIdx.x;
    int lane = tid & 63;
    int wid  = tid >> 6;      // 0..7
    int wm   = wid >> 2;      // M half (128 rows)
    int wn   = wid & 3;       // h quarter (16 cols x 4 gates)
    int fr   = lane & 15, fk = lane >> 4;

    // fragment-load base pointers (u16 units); strides: A kt=4096, m=512; W kt=2048, g=512
    const u16* pA = Ap + ((size_t)(mi * 2 + wm)) * (64 * 8 * 64 * 8) + lane * 8;
    const u16* pW = Wp + ((size_t)(hq * 4 + wn)) * (64 * 4 * 64 * 8) + lane * 8;

#define LD8(p) __builtin_bit_cast(half8, *(const short8*)(p))

#define LOADF(AA, WW, kt) do { \
        _Pragma("unroll") \
        for (int m = 0; m < 8; ++m) AA[m] = LD8(pA + (size_t)(kt) * 4096 + m * 512); \
        _Pragma("unroll") \
        for (int g = 0; g < 4; ++g) WW[g] = LD8(pW + (size_t)(kt) * 2048 + g * 512); \
    } while (0)

#define DOMFMA(AA, WW) do { \
        __builtin_amdgcn_s_setprio(1); \
        _Pragma("unroll") \
        for (int g = 0; g < 4; ++g) \
            _Pragma("unroll") \
            for (int m = 0; m < 8; ++m) \
                acc[m][g] = __builtin_amdgcn_mfma_f32_16x16x32_f16(AA[m], WW[g], acc[m][g], 0, 0, 0); \
        __builtin_amdgcn_s_setprio(0); \
    } while (0)

    f32x4 acc[8][4];
#pragma unroll
    for (int m = 0; m < 8; ++m)
#pragma unroll
        for (int g = 0; g < 4; ++g)
            acc[m][g] = (f32x4){0.f, 0.f, 0.f, 0.f};

    half8 aX[8], wX[4], aY[8], wY[4];
    LOADF(aX, wX, 0);

#pragma unroll 1
    for (int t = 0; t < T_STEPS; t += 2) {
        LOADF(aY, wY, t + 1);          // prefetch odd step into Y
        DOMFMA(aX, wX);                // compute even step (compiler waits only on X)
        if (t + 2 < T_STEPS) LOADF(aX, wX, t + 2);   // prefetch next even into X
        DOMFMA(aY, wY);                // compute odd step
    }

    // ---- epilogue: all 4 gates for (r,h) are lane-local ----
    float sq_e = sqrtf(noise_e[0]);
    float sq_q = sqrtf(noise_q[0]);
    int h = h0 + wn * 16 + fr;
    float bsum[4];
#pragma unroll
    for (int g = 0; g < 4; ++g)
        bsum[g] = bias_ih[g * 1024 + h] + bias_hh[g * 1024 + h];
#pragma unroll
    for (int m = 0; m < 8; ++m) {
        int r0 = bm0 + wm * 128 + m * 16 + fk * 4;
#pragma unroll
        for (int j = 0; j < 4; ++j) {
            int r = r0 + j;
            float gi = acc[m][0][j] + bsum[0];
            float gf = acc[m][1][j] + bsum[1];
            float gc = acc[m][2][j] + bsum[2];
            float go = acc[m][3][j] + bsum[3];
            float ig = sigmf(gi), fg = sigmf(gf);
            float cg = tanhfast(gc), og = sigmf(go);
            size_t off = (size_t)r * HDIM + h;
            float cyv = fg * cx[off] + ig * cg + sq_e * eps_c[off];
            float hyv = og * tanhfast(cyv) + sq_q * eps_h[off];
            out[off] = hyv;                                 // hy
            out[(size_t)B_ROWS * HDIM + off] = cyv;         // cy
        }
    }
}

extern "C" void kernel_launch(void* const* d_in, const int* in_sizes, int n_in,
                              void* d_out, int out_size, void* d_ws, size_t ws_size,
                              hipStream_t stream)
{
    const float* input = (const float*)d_in[0];
    const float* hx    = (const float*)d_in[1];
    const float* cx    = (const float*)d_in[2];
    const float* nq    = (const float*)d_in[3];
    const float* ne    = (const float*)d_in[4];
    const float* wih   = (const float*)d_in[5];
    const float* whh   = (const float*)d_in[6];
    const float* bih   = (const float*)d_in[7];
    const float* bhh   = (const float*)d_in[8];
    const float* epsc  = (const float*)d_in[9];
    const float* epsh  = (const float*)d_in[10];
    float* out = (float*)d_out;

    u16* Ap = (u16*)d_ws;
    u16* Wp = Ap + (size_t)B_ROWS * KDIM;   // 32 MB of ws total

    hipLaunchKernelGGL(pack_kernel, dim3(2048), dim3(256), 0, stream,
                       input, hx, wih, whh, Ap, Wp);
    hipLaunchKernelGGL(lstm_fused, dim3(256), dim3(512), 0, stream,
                       Ap, Wp, cx, epsc, epsh, bih, bhh, nq, ne, out);
}